// Round 1
// baseline (149.596 us; speedup 1.0000x reference)
//
#include <hip/hip_runtime.h>

// MultiHeadAttention fused pipeline for MI355X (gfx950).
// B=8, N=1024, DIM=192, HEADS=3, DH=64. All inputs fp32; intermediates bf16
// where traffic-dominant; accumulation fp32 everywhere.
//
// Workspace layout (bytes), total ~69.5 MB:
//   xb   @ 0          : 3,145,728   x cast to bf16 [8192][192]
//   wt   @ 3,145,728  : 221,184     W_qkv^T bf16 [576][192]
//   q    @ 3,366,912  : 3,145,728   [bh][n][d] bf16
//   k    @ 6,512,640  : 3,145,728   [bh][n][d] bf16
//   vt   @ 9,658,368  : 3,145,728   [bh][d][n] bf16
//   a    @ 12,804,096 : 50,331,648  [bh][i][j] bf16 (post conv2+relu, pre-gate)
//   o    @ 63,135,744 : 6,291,456   [n][h*64+d] f32
//   part @ 69,427,200 : 12,288      [bh][128] f32 partial sums (SE pool)
//   cw   @ 69,439,488 : 96          [bh] f32 sigmoid gates

typedef unsigned short u16;
typedef unsigned int u32;
using f32x4 = __attribute__((ext_vector_type(4))) float;
using short8 = __attribute__((ext_vector_type(8))) short;

__device__ inline u16 f2bf(float f) {
  u32 u = __builtin_bit_cast(u32, f);
  u32 r = (u + 0x7FFFu + ((u >> 16) & 1u)) >> 16;
  return (u16)r;
}
__device__ inline float bf2f(u16 v) {
  u32 u = ((u32)v) << 16;
  return __builtin_bit_cast(float, u);
}
__device__ inline short8 asfrag(uint4 v) { return __builtin_bit_cast(short8, v); }

// ---------------- K0a: cast x -> bf16 ----------------
__global__ __launch_bounds__(256) void mha_cvt_x(const float* __restrict__ x,
                                                 u16* __restrict__ xb) {
  int i = blockIdx.x * 256 + threadIdx.x;  // 393216 threads, 4 elems each
  float4 v = *(const float4*)(x + (size_t)i * 4);
  u16 pk[4] = {f2bf(v.x), f2bf(v.y), f2bf(v.z), f2bf(v.w)};
  *(uint2*)(xb + (size_t)i * 4) = *(const uint2*)pk;
}

// ---------------- K0b: transpose W_qkv -> wt bf16 [576][192] ----------------
__global__ __launch_bounds__(256) void mha_wt(const float* __restrict__ wq,
                                              u16* __restrict__ wt) {
  int i = blockIdx.x * 256 + threadIdx.x;  // 110592
  int c = i / 192, kk = i - c * 192;
  wt[i] = f2bf(wq[(size_t)kk * 576 + c]);
}

// ---------------- K1: qkv projection ----------------
// grid (128 mblocks of 64 rows, 9 col-tiles of 64), 256 threads (4 waves).
// nt 0-2 -> q head nt; 3-5 -> k; 6-8 -> v (stored transposed).
__global__ __launch_bounds__(256) void mha_qkv(const u16* __restrict__ xb,
                                               const u16* __restrict__ wt,
                                               u16* __restrict__ q,
                                               u16* __restrict__ kmat,
                                               u16* __restrict__ vt) {
  __shared__ u16 tile[64][72];
  int mb = blockIdx.x, nt = blockIdx.y;
  int tid = threadIdx.x, w = tid >> 6, l = tid & 63;
  int lr = l & 15, lg = l >> 4;
  int m0 = mb * 64 + w * 16;
  const u16* xrow = xb + (size_t)(m0 + lr) * 192;
  uint4 af[6];
#pragma unroll
  for (int s = 0; s < 6; ++s) af[s] = *(const uint4*)(xrow + s * 32 + lg * 8);
#pragma unroll
  for (int ct = 0; ct < 4; ++ct) {
    int c = nt * 64 + ct * 16 + lr;
    const u16* wrow = wt + (size_t)c * 192;
    f32x4 acc = {0.f, 0.f, 0.f, 0.f};
#pragma unroll
    for (int s = 0; s < 6; ++s) {
      uint4 bf = *(const uint4*)(wrow + s * 32 + lg * 8);
      acc = __builtin_amdgcn_mfma_f32_16x16x32_bf16(asfrag(af[s]), asfrag(bf), acc, 0, 0, 0);
    }
#pragma unroll
    for (int r = 0; r < 4; ++r) tile[w * 16 + 4 * lg + r][ct * 16 + lr] = f2bf(acc[r]);
  }
  __syncthreads();
  int typ = nt / 3, head = nt - typ * 3;
  int b = mb >> 4, n0 = (mb & 15) << 6;
  size_t bh = (size_t)(b * 3 + head);
  if (typ < 2) {
    u16* dst = (typ == 0 ? q : kmat) + bh * 65536;
#pragma unroll
    for (int it = 0; it < 2; ++it) {
      int id = tid + it * 256;
      int rr = id >> 3, ch = id & 7;
      uint4 vv = *(const uint4*)&tile[rr][ch * 8];
      *(uint4*)(dst + (size_t)(n0 + rr) * 64 + ch * 8) = vv;
    }
  } else {
    u16* dst = vt + bh * 65536;
#pragma unroll
    for (int it = 0; it < 2; ++it) {
      int id = tid + it * 256;
      int d = id >> 3, ch = id & 7;
      u16 pk[8];
#pragma unroll
      for (int e = 0; e < 8; ++e) pk[e] = tile[ch * 8 + e][d];
      *(uint4*)(dst + (size_t)d * 1024 + n0 + ch * 8) = *(const uint4*)pk;
    }
  }
}

// ---------------- K2: fused QK^T + conv1+bn+relu + conv2+bn+relu + pool ----------------
// grid 3072 = bh(24) * rowblock(32) * colstrip(4); 256 threads.
// S: scaled dots rows r0-2..r0+33, cols s0-2..s0+257 (zero for global OOB).
// C1: conv1 out rows r0-1..r0+32, cols s0-1..s0+256 (zero for global OOB).
__global__ __launch_bounds__(256) void mha_qkconv(
    const u16* __restrict__ q, const u16* __restrict__ kmat,
    const float* __restrict__ c1w, const float* __restrict__ c1b,
    const float* __restrict__ g1, const float* __restrict__ bb1,
    const float* __restrict__ c2w, const float* __restrict__ c2b,
    const float* __restrict__ g2, const float* __restrict__ bb2,
    u16* __restrict__ a, float* __restrict__ partial) {
  __shared__ u16 S[36][264];
  __shared__ u16 C1[34][264];
  __shared__ float wred[4];
  int bid = blockIdx.x;
  int st = bid & 3, rb = (bid >> 2) & 31, bh = bid >> 7;
  int h = bh - (bh / 3) * 3;
  int r0 = rb * 32, s0 = st * 256;
  int tid = threadIdx.x, w = tid >> 6, l = tid & 63;
  int lr = l & 15, lg = l >> 4;
  const u16* qb = q + (size_t)bh * 65536;
  const u16* kb = kmat + (size_t)bh * 65536;
  // ---- phase 1: QK^T * SCALE into S ----
  uint4 af[3][2];
#pragma unroll
  for (int m = 0; m < 3; ++m) {
    int gi = r0 - 2 + 16 * m + lr;
    bool ok = (gi >= 0) && (gi < 1024);
#pragma unroll
    for (int kk = 0; kk < 2; ++kk)
      af[m][kk] = ok ? *(const uint4*)(qb + (size_t)gi * 64 + kk * 32 + lg * 8)
                     : make_uint4(0, 0, 0, 0);
  }
  for (int n = w; n < 17; n += 4) {
    int gj = s0 - 2 + 16 * n + lr;
    bool ok = (gj >= 0) && (gj < 1024);
    uint4 bf0 = ok ? *(const uint4*)(kb + (size_t)gj * 64 + lg * 8) : make_uint4(0, 0, 0, 0);
    uint4 bf1 = ok ? *(const uint4*)(kb + (size_t)gj * 64 + 32 + lg * 8) : make_uint4(0, 0, 0, 0);
#pragma unroll
    for (int m = 0; m < 3; ++m) {
      f32x4 acc = {0.f, 0.f, 0.f, 0.f};
      acc = __builtin_amdgcn_mfma_f32_16x16x32_bf16(asfrag(af[m][0]), asfrag(bf0), acc, 0, 0, 0);
      acc = __builtin_amdgcn_mfma_f32_16x16x32_bf16(asfrag(af[m][1]), asfrag(bf1), acc, 0, 0, 0);
      int sj = 16 * n + lr;
      if (sj < 260) {
#pragma unroll
        for (int r = 0; r < 4; ++r) {
          int si = 16 * m + 4 * lg + r;
          if (si < 36) S[si][sj] = f2bf(acc[r] * 0.125f);
        }
      }
    }
  }
  __syncthreads();
  // ---- phase 2: conv1 + bn + relu -> C1 ----
  float sc1 = g1[h] / sqrtf(1.00001f);
  float wc1[9];
#pragma unroll
  for (int i = 0; i < 9; ++i) wc1[i] = c1w[h * 9 + i] * sc1;
  float bias1 = c1b[h] * sc1 + bb1[h];
  for (int idx = tid; idx < 34 * 33; idx += 256) {
    int ci = idx / 33;
    int u = idx - ci * 33;
    int cj0 = u * 8;
    int gr = r0 - 1 + ci;
    float out[8];
#pragma unroll
    for (int e = 0; e < 8; ++e) out[e] = bias1;
    bool rok = (gr >= 0) && (gr < 1024);
    if (rok) {
#pragma unroll
      for (int di = 0; di < 3; ++di) {
        const u16* Sr = &S[ci + di][0];
        uint4 ch0 = *(const uint4*)(Sr + cj0);
        uint4 ch1 = make_uint4(0, 0, 0, 0);
        if (cj0 < 256) ch1 = *(const uint4*)(Sr + cj0 + 8);
        const u16* p0 = (const u16*)&ch0;
        const u16* p1 = (const u16*)&ch1;
        float v[10];
#pragma unroll
        for (int xx = 0; xx < 8; ++xx) v[xx] = bf2f(p0[xx]);
        v[8] = bf2f(p1[0]);
        v[9] = bf2f(p1[1]);
        float w0 = wc1[di * 3 + 0], w1 = wc1[di * 3 + 1], w2 = wc1[di * 3 + 2];
#pragma unroll
        for (int e = 0; e < 8; ++e) out[e] += w0 * v[e] + w1 * v[e + 1] + w2 * v[e + 2];
      }
    }
    u16 pk[8];
#pragma unroll
    for (int e = 0; e < 8; ++e) {
      int gc = s0 - 1 + cj0 + e;
      float val = (rok && gc >= 0 && gc < 1024) ? fmaxf(out[e], 0.f) : 0.f;
      pk[e] = f2bf(val);
    }
    *(uint4*)&C1[ci][cj0] = *(const uint4*)pk;
  }
  __syncthreads();
  // ---- phase 3: conv2 + bn + relu -> a (global) + pool partial ----
  float sc2 = g2[h] / sqrtf(1.00001f);
  float wc2[9];
#pragma unroll
  for (int i = 0; i < 9; ++i) wc2[i] = c2w[h * 9 + i] * sc2;
  float bias2 = c2b[h] * sc2 + bb2[h];
  float lsum = 0.f;
  u16* ab = a + (size_t)bh * 1048576;
  for (int idx = tid; idx < 32 * 32; idx += 256) {
    int ai = idx >> 5, u = idx & 31;
    int aj0 = u * 8;
    float out[8];
#pragma unroll
    for (int e = 0; e < 8; ++e) out[e] = bias2;
#pragma unroll
    for (int di = 0; di < 3; ++di) {
      const u16* Cr = &C1[ai + di][0];
      uint4 ch0 = *(const uint4*)(Cr + aj0);
      uint4 ch1 = *(const uint4*)(Cr + aj0 + 8);
      const u16* p0 = (const u16*)&ch0;
      const u16* p1 = (const u16*)&ch1;
      float v[10];
#pragma unroll
      for (int xx = 0; xx < 8; ++xx) v[xx] = bf2f(p0[xx]);
      v[8] = bf2f(p1[0]);
      v[9] = bf2f(p1[1]);
      float w0 = wc2[di * 3 + 0], w1 = wc2[di * 3 + 1], w2 = wc2[di * 3 + 2];
#pragma unroll
      for (int e = 0; e < 8; ++e) out[e] += w0 * v[e] + w1 * v[e + 1] + w2 * v[e + 2];
    }
    u16 pk[8];
#pragma unroll
    for (int e = 0; e < 8; ++e) {
      float val = fmaxf(out[e], 0.f);
      lsum += val;
      pk[e] = f2bf(val);
    }
    *(uint4*)(ab + (size_t)(r0 + ai) * 1024 + s0 + aj0) = *(const uint4*)pk;
  }
#pragma unroll
  for (int off = 32; off; off >>= 1) lsum += __shfl_xor(lsum, off);
  if (l == 0) wred[w] = lsum;
  __syncthreads();
  if (tid == 0) partial[bid] = wred[0] + wred[1] + wred[2] + wred[3];
}

// ---------------- K3: SE gate (cw) ----------------
__global__ __launch_bounds__(64) void mha_cw(const float* __restrict__ partial,
                                             const float* __restrict__ w1,
                                             const float* __restrict__ b1,
                                             const float* __restrict__ w2,
                                             const float* __restrict__ b2,
                                             float* __restrict__ cw) {
  int t = threadIdx.x;
  if (t < 24) {
    int b = t / 3, h = t - 3 * b;
    float pm[3];
    for (int hh = 0; hh < 3; ++hh) {
      float s = 0.f;
      for (int i = 0; i < 128; ++i) s += partial[(b * 3 + hh) * 128 + i];
      pm[hh] = s * (1.f / 1048576.f);
    }
    float hid = pm[0] * w1[0] + pm[1] * w1[1] + pm[2] * w1[2] + b1[0];
    hid = fmaxf(hid, 0.f);
    float z = hid * w2[h] + b2[h];
    cw[t] = 1.f / (1.f + __expf(-z));
  }
}

// ---------------- K5: softmax(cw*a) + PV ----------------
// grid 768 = bh(24)*rowblock(32); 512 threads (8 waves). Dynamic LDS 67584B:
//   [0,65536)      attn tile 32x1024 bf16, 16B chunks XOR-swizzled by ((row&7)<<4)
//   [65536,66560)  redm [32][8]   [66560,67584) reds [32][8]
__global__ __launch_bounds__(512) void mha_smpv(const u16* __restrict__ a,
                                                const u16* __restrict__ vt,
                                                const float* __restrict__ cw,
                                                float* __restrict__ o) {
  extern __shared__ char smem[];
  float* redm = (float*)(smem + 65536);
  float* reds = (float*)(smem + 66560);
  int bid = blockIdx.x;
  int rb = bid & 31, bh = bid >> 5;
  int b = bh / 3, h = bh - 3 * b;
  int n0 = rb * 32;
  int tid = threadIdx.x, w = tid >> 6, l = tid & 63;
  float cwv = cw[bh];
  const u16* ab = a + (size_t)bh * 1048576 + (size_t)n0 * 1024;
  // stage a tile
#pragma unroll
  for (int it = 0; it < 8; ++it) {
    int id = tid + it * 512;
    int row = id >> 7, ch = id & 127;
    uint4 vv = *(const uint4*)(ab + (size_t)row * 1024 + ch * 8);
    *(uint4*)(smem + row * 2048 + ((ch * 16) ^ ((row & 7) << 4))) = vv;
  }
  __syncthreads();
  // softmax: row = tid&31, portion p = tid>>5 (64 cols each)
  int row = tid & 31, p = tid >> 5;
  uint4 vals[8];
  float mx = -3.4e38f;
#pragma unroll
  for (int i = 0; i < 8; ++i) {
    int ch = p * 8 + i;
    vals[i] = *(const uint4*)(smem + row * 2048 + ((ch * 16) ^ ((row & 7) << 4)));
    const u16* pv = (const u16*)&vals[i];
#pragma unroll
    for (int e = 0; e < 8; ++e) mx = fmaxf(mx, bf2f(pv[e]));
  }
  mx = fmaxf(mx, __shfl_xor(mx, 32));
  redm[row * 8 + w] = mx;
  __syncthreads();
  float fm = redm[row * 8];
#pragma unroll
  for (int i = 1; i < 8; ++i) fm = fmaxf(fm, redm[row * 8 + i]);
  fm *= cwv;
  float lsum = 0.f;
#pragma unroll
  for (int i = 0; i < 8; ++i) {
    const u16* pv = (const u16*)&vals[i];
    u16 pk[8];
#pragma unroll
    for (int e = 0; e < 8; ++e) {
      float ex = __expf(bf2f(pv[e]) * cwv - fm);
      u16 qq = f2bf(ex);
      lsum += bf2f(qq);
      pk[e] = qq;
    }
    int ch = p * 8 + i;
    *(uint4*)(smem + row * 2048 + ((ch * 16) ^ ((row & 7) << 4))) = *(const uint4*)pk;
  }
  lsum += __shfl_xor(lsum, 32);
  reds[row * 8 + w] = lsum;
  __syncthreads();
  // PV: wave -> (colt = w&3, rt = w>>2) 16x16 output tile, K=1024
  int colt = w & 3, rt = w >> 2;
  int lr = l & 15, lg = l >> 4;
  const u16* vb = vt + ((size_t)bh * 64 + colt * 16 + lr) * 1024;
  f32x4 acc = {0.f, 0.f, 0.f, 0.f};
  for (int kt = 0; kt < 32; ++kt) {
    int arow = rt * 16 + lr;
    int ch = kt * 4 + lg;
    uint4 afr = *(const uint4*)(smem + arow * 2048 + ((ch * 16) ^ ((arow & 7) << 4)));
    uint4 bfr = *(const uint4*)(vb + kt * 32 + lg * 8);
    acc = __builtin_amdgcn_mfma_f32_16x16x32_bf16(asfrag(afr), asfrag(bfr), acc, 0, 0, 0);
  }
  float* ob = o + (size_t)(b * 1024 + n0) * 192 + h * 64 + colt * 16 + lr;
#pragma unroll
  for (int r = 0; r < 4; ++r) {
    int rr = rt * 16 + 4 * lg + r;
    float s = 0.f;
#pragma unroll
    for (int i = 0; i < 8; ++i) s += reds[rr * 8 + i];
    ob[(size_t)rr * 192] = acc[r] / s;
  }
}

// ---------------- K6: output projection (fp32 vector) ----------------
// grid (128, 3); 256 threads; each thread a 4x4 output tile.
__global__ __launch_bounds__(256) void mha_proj(const float* __restrict__ o,
                                                const float* __restrict__ W,
                                                const float* __restrict__ bo,
                                                float* __restrict__ out) {
  __shared__ float ot[64 * 196];
  int nb = blockIdx.x, cb = blockIdx.y;
  int t = threadIdx.x;
  for (int r = 0; r < 64; ++r) {
    if (t < 192) ot[r * 196 + t] = o[(size_t)(nb * 64 + r) * 192 + t];
  }
  __syncthreads();
  int r0 = (t >> 4) * 4;
  int c0 = cb * 64 + (t & 15) * 4;
  float acc[4][4];
#pragma unroll
  for (int i = 0; i < 4; ++i)
#pragma unroll
    for (int j = 0; j < 4; ++j) acc[i][j] = 0.f;
  for (int kx = 0; kx < 192; ++kx) {
    f32x4 wv = *(const f32x4*)(W + (size_t)kx * 192 + c0);
    float ov[4];
#pragma unroll
    for (int i = 0; i < 4; ++i) ov[i] = ot[(r0 + i) * 196 + kx];
#pragma unroll
    for (int i = 0; i < 4; ++i)
#pragma unroll
      for (int j = 0; j < 4; ++j) acc[i][j] += ov[i] * wv[j];
  }
#pragma unroll
  for (int i = 0; i < 4; ++i)
#pragma unroll
    for (int j = 0; j < 4; ++j)
      out[(size_t)(nb * 64 + r0 + i) * 192 + c0 + j] = acc[i][j] + bo[c0 + j];
}

extern "C" void kernel_launch(void* const* d_in, const int* in_sizes, int n_in,
                              void* d_out, int out_size, void* d_ws, size_t ws_size,
                              hipStream_t stream) {
  (void)in_sizes; (void)n_in; (void)out_size; (void)ws_size;
  const float* x    = (const float*)d_in[0];
  const float* wqkv = (const float*)d_in[1];
  const float* c1w  = (const float*)d_in[2];
  const float* c1b  = (const float*)d_in[3];
  const float* g1   = (const float*)d_in[4];
  const float* b1   = (const float*)d_in[5];
  const float* c2w  = (const float*)d_in[6];
  const float* c2b  = (const float*)d_in[7];
  const float* g2   = (const float*)d_in[8];
  const float* b2   = (const float*)d_in[9];
  const float* caw1 = (const float*)d_in[10];
  const float* cab1 = (const float*)d_in[11];
  const float* caw2 = (const float*)d_in[12];
  const float* cab2 = (const float*)d_in[13];
  const float* wout = (const float*)d_in[14];
  const float* bout = (const float*)d_in[15];
  float* out = (float*)d_out;
  char* ws = (char*)d_ws;  // requires ws_size >= ~69.5 MB

  u16* xb = (u16*)(ws + 0);
  u16* wt = (u16*)(ws + 3145728);
  u16* q  = (u16*)(ws + 3366912);
  u16* k  = (u16*)(ws + 6512640);
  u16* vt = (u16*)(ws + 9658368);
  u16* a  = (u16*)(ws + 12804096);
  float* o       = (float*)(ws + 63135744);
  float* partial = (float*)(ws + 69427200);
  float* cwbuf   = (float*)(ws + 69439488);

  mha_cvt_x<<<1536, 256, 0, stream>>>(x, xb);
  mha_wt<<<432, 256, 0, stream>>>(wqkv, wt);
  mha_qkv<<<dim3(128, 9), 256, 0, stream>>>(xb, wt, q, k, vt);
  mha_qkconv<<<3072, 256, 0, stream>>>(q, k, c1w, c1b, g1, b1, c2w, c2b, g2, b2, a, partial);
  mha_cw<<<1, 64, 0, stream>>>(partial, caw1, cab1, caw2, cab2, cwbuf);
  hipFuncSetAttribute(reinterpret_cast<const void*>(mha_smpv),
                      hipFuncAttributeMaxDynamicSharedMemorySize, 67584);
  mha_smpv<<<768, 512, 67584, stream>>>(a, vt, cwbuf, o);
  mha_proj<<<dim3(128, 3), 256, 0, stream>>>(o, wout, bout, out);
}

// Round 2
// 145.553 us; speedup vs baseline: 1.0278x; 1.0278x over previous
//
#include <hip/hip_runtime.h>

// MultiHeadAttention fused pipeline for MI355X (gfx950).
// B=8, N=1024, DIM=192, HEADS=3, DH=64.
//
// Workspace layout (bytes):
//   partial @ 0        : 24,576   [bh][256] f32 SE-pool partials (overlaps dead xb)
//   cw      @ 24,576   : 96       [bh] f32 gates (overlaps dead xb)
//   xb      @ 0        : 3,145,728   x bf16 [8192][192]  (dead after K1; K2 writes partial over it)
//   wt      @ 3,145,728: 221,184     W_qkv^T bf16 [576][192]
//   q       @ 3,366,912: 3,145,728   [bh][n][d] bf16
//   k       @ 6,512,640: 3,145,728   [bh][n][d] bf16
//   vt      @ 9,658,368: 3,145,728   [bh][d][n] bf16
//   a       @ 12,804,096: 50,331,648 [bh][i][j] bf16
//   o       @ 63,135,744: 6,291,456  [n][h*64+d] f32     (max byte = 69,427,200)

typedef unsigned short u16;
typedef unsigned int u32;
using f32x4 = __attribute__((ext_vector_type(4))) float;
using short8 = __attribute__((ext_vector_type(8))) short;

__device__ inline u16 f2bf(float f) {
  u32 u = __builtin_bit_cast(u32, f);
  u32 r = (u + 0x7FFFu + ((u >> 16) & 1u)) >> 16;
  return (u16)r;
}
__device__ inline float bf2f(u16 v) {
  u32 u = ((u32)v) << 16;
  return __builtin_bit_cast(float, u);
}
__device__ inline short8 asfrag(uint4 v) { return __builtin_bit_cast(short8, v); }

// ---------------- K0a: cast x -> bf16 ----------------
__global__ __launch_bounds__(256) void mha_cvt_x(const float* __restrict__ x,
                                                 u16* __restrict__ xb) {
  int i = blockIdx.x * 256 + threadIdx.x;
  float4 v = *(const float4*)(x + (size_t)i * 4);
  u16 pk[4] = {f2bf(v.x), f2bf(v.y), f2bf(v.z), f2bf(v.w)};
  *(uint2*)(xb + (size_t)i * 4) = *(const uint2*)pk;
}

// ---------------- K0b: transpose W_qkv -> wt bf16 [576][192] ----------------
__global__ __launch_bounds__(256) void mha_wt(const float* __restrict__ wq,
                                              u16* __restrict__ wt) {
  int i = blockIdx.x * 256 + threadIdx.x;
  int c = i / 192, kk = i - c * 192;
  wt[i] = f2bf(wq[(size_t)kk * 576 + c]);
}

// ---------------- K1: qkv projection ----------------
// grid (128,3): x-block = 64 rows; y: 0->q(heads 0-2), 1->k, 2->v(transposed).
__global__ __launch_bounds__(256) void mha_qkv(const u16* __restrict__ xb,
                                               const u16* __restrict__ wt,
                                               u16* __restrict__ q,
                                               u16* __restrict__ kmat,
                                               u16* __restrict__ vt) {
  __shared__ u16 tile[64][72];
  int mb = blockIdx.x, gy = blockIdx.y;
  int tid = threadIdx.x, w = tid >> 6, l = tid & 63;
  int lr = l & 15, lg = l >> 4;
  int m0 = mb * 64 + w * 16;
  const u16* xrow = xb + (size_t)(m0 + lr) * 192;
  uint4 af[6];
#pragma unroll
  for (int s = 0; s < 6; ++s) af[s] = *(const uint4*)(xrow + s * 32 + lg * 8);
  int b = mb >> 4, n0 = (mb & 15) << 6;
  for (int i = 0; i < 3; ++i) {
    int nt = gy * 3 + i;
#pragma unroll
    for (int ct = 0; ct < 4; ++ct) {
      int c = nt * 64 + ct * 16 + lr;
      const u16* wrow = wt + (size_t)c * 192;
      f32x4 acc = {0.f, 0.f, 0.f, 0.f};
#pragma unroll
      for (int s = 0; s < 6; ++s) {
        uint4 bf = *(const uint4*)(wrow + s * 32 + lg * 8);
        acc = __builtin_amdgcn_mfma_f32_16x16x32_bf16(asfrag(af[s]), asfrag(bf), acc, 0, 0, 0);
      }
#pragma unroll
      for (int r = 0; r < 4; ++r) tile[w * 16 + 4 * lg + r][ct * 16 + lr] = f2bf(acc[r]);
    }
    __syncthreads();
    int typ = gy, head = i;
    size_t bh = (size_t)(b * 3 + head);
    if (typ < 2) {
      u16* dst = (typ == 0 ? q : kmat) + bh * 65536;
#pragma unroll
      for (int it = 0; it < 2; ++it) {
        int id = tid + it * 256;
        int rr = id >> 3, ch = id & 7;
        uint4 vv = *(const uint4*)&tile[rr][ch * 8];
        *(uint4*)(dst + (size_t)(n0 + rr) * 64 + ch * 8) = vv;
      }
    } else {
      u16* dst = vt + bh * 65536;
#pragma unroll
      for (int it = 0; it < 2; ++it) {
        int id = tid + it * 256;
        int d = id >> 3, ch = id & 7;
        u16 pk[8];
#pragma unroll
        for (int e = 0; e < 8; ++e) pk[e] = tile[ch * 8 + e][d];
        *(uint4*)(dst + (size_t)d * 1024 + n0 + ch * 8) = *(const uint4*)pk;
      }
    }
    __syncthreads();
  }
}

// ---------------- K2: fused QK^T + conv1+bn+relu + conv2+bn+relu + pool ----------------
// grid 6144 = bh(24)*rowblock(32)*colstrip(8); 256 threads. 32x128 output tile.
// All LDS in f32; 16B chunks XOR-swizzled by ((row&7)<<4). Row stride 544 B (136 f32).
__global__ __launch_bounds__(256) void mha_qkconv(
    const u16* __restrict__ q, const u16* __restrict__ kmat,
    const float* __restrict__ c1w, const float* __restrict__ c1b,
    const float* __restrict__ g1, const float* __restrict__ bb1,
    const float* __restrict__ c2w, const float* __restrict__ c2b,
    const float* __restrict__ g2, const float* __restrict__ bb2,
    u16* __restrict__ a, float* __restrict__ partial) {
  __shared__ float S[36 * 136];   // rows r0-2..r0+33, cols s0-2..s0+129 (+pad)
  __shared__ float C1[34 * 136];  // rows r0-1..r0+32, cols s0-1..s0+128 (+pad)
  __shared__ float wred[4];
  int bid = blockIdx.x;
  int st = bid & 7, rb = (bid >> 3) & 31, bh = bid >> 8;
  int h = bh - (bh / 3) * 3;
  int r0 = rb * 32, s0 = st * 128;
  int tid = threadIdx.x, w = tid >> 6, l = tid & 63;
  int lr = l & 15, lg = l >> 4;
  const u16* qb = q + (size_t)bh * 65536;
  const u16* kb = kmat + (size_t)bh * 65536;
  char* Sb = (char*)S;
  char* Cb = (char*)C1;
  // ---- phase 1: QK^T * SCALE -> S (f32, swizzled) ----
  uint4 af[3][2];
#pragma unroll
  for (int m = 0; m < 3; ++m) {
    int gi = r0 - 2 + 16 * m + lr;
    bool ok = (gi >= 0) && (gi < 1024);
#pragma unroll
    for (int kk = 0; kk < 2; ++kk)
      af[m][kk] = ok ? *(const uint4*)(qb + (size_t)gi * 64 + kk * 32 + lg * 8)
                     : make_uint4(0, 0, 0, 0);
  }
#pragma unroll
  for (int t = 0; t < 3; ++t) {
    int n = w + 4 * t;
    if (n >= 9) break;
    int gj = s0 - 2 + 16 * n + lr;
    bool ok = (gj >= 0) && (gj < 1024);
    uint4 bf0 = ok ? *(const uint4*)(kb + (size_t)gj * 64 + lg * 8) : make_uint4(0, 0, 0, 0);
    uint4 bf1 = ok ? *(const uint4*)(kb + (size_t)gj * 64 + 32 + lg * 8) : make_uint4(0, 0, 0, 0);
    int sjl = 16 * n + lr;
#pragma unroll
    for (int m = 0; m < 3; ++m) {
      f32x4 acc = {0.f, 0.f, 0.f, 0.f};
      acc = __builtin_amdgcn_mfma_f32_16x16x32_bf16(asfrag(af[m][0]), asfrag(bf0), acc, 0, 0, 0);
      acc = __builtin_amdgcn_mfma_f32_16x16x32_bf16(asfrag(af[m][1]), asfrag(bf1), acc, 0, 0, 0);
      if (sjl < 132) {
#pragma unroll
        for (int r = 0; r < 4; ++r) {
          int si = 16 * m + 4 * lg + r;
          if (si < 36)
            *(float*)(Sb + si * 544 + ((((sjl >> 2) << 4) ^ ((si & 7) << 4))) + ((sjl & 3) << 2)) =
                acc[r] * 0.125f;
        }
      }
    }
  }
  __syncthreads();
  // ---- phase 2: conv1+bn+relu -> C1 (f32) ----
  float sc1 = g1[h] / sqrtf(1.00001f);
  float wc1[9];
#pragma unroll
  for (int i = 0; i < 9; ++i) wc1[i] = c1w[h * 9 + i] * sc1;
  float bias1 = c1b[h] * sc1 + bb1[h];
  for (int idx = tid; idx < 34 * 33; idx += 256) {
    int ci = idx / 33, u = idx - ci * 33;
    int col0 = 4 * u;  // C1 col base; uses S floats col0..col0+5
    int gr = r0 - 1 + ci;
    bool rok = (gr >= 0) && (gr < 1024);
    f32x4 res = {bias1, bias1, bias1, bias1};
    if (rok) {
#pragma unroll
      for (int di = 0; di < 3; ++di) {
        int srow = ci + di;
        const char* sb = Sb + srow * 544;
        int c = col0 >> 2;
        int swz = (srow & 7) << 4;
        f32x4 va = *(const f32x4*)(sb + ((c << 4) ^ swz));
        f32x4 vb = *(const f32x4*)(sb + (((c + 1) << 4) ^ swz));
        float w0 = wc1[di * 3 + 0], w1 = wc1[di * 3 + 1], w2 = wc1[di * 3 + 2];
        res[0] += w0 * va[0] + w1 * va[1] + w2 * va[2];
        res[1] += w0 * va[1] + w1 * va[2] + w2 * va[3];
        res[2] += w0 * va[2] + w1 * va[3] + w2 * vb[0];
        res[3] += w0 * va[3] + w1 * vb[0] + w2 * vb[1];
      }
    }
    f32x4 outv;
#pragma unroll
    for (int e = 0; e < 4; ++e) {
      int gc = s0 - 1 + col0 + e;
      outv[e] = (rok && gc >= 0 && gc < 1024) ? fmaxf(res[e], 0.f) : 0.f;
    }
    *(f32x4*)(Cb + ci * 544 + (((col0 >> 2) << 4) ^ ((ci & 7) << 4))) = outv;
  }
  __syncthreads();
  // ---- phase 3: conv2+bn+relu -> a (bf16 global) + pool ----
  float sc2 = g2[h] / sqrtf(1.00001f);
  float wc2[9];
#pragma unroll
  for (int i = 0; i < 9; ++i) wc2[i] = c2w[h * 9 + i] * sc2;
  float bias2 = c2b[h] * sc2 + bb2[h];
  float lsum = 0.f;
  u16* ab = a + (size_t)bh * 1048576;
#pragma unroll
  for (int it = 0; it < 4; ++it) {
    int idx = tid + it * 256;
    int ai = idx >> 5, u = idx & 31;
    int col0 = 4 * u;  // a col; uses C1 floats col0..col0+5
    f32x4 res = {bias2, bias2, bias2, bias2};
#pragma unroll
    for (int di = 0; di < 3; ++di) {
      int crow = ai + di;
      const char* cb = Cb + crow * 544;
      int c = col0 >> 2;
      int swz = (crow & 7) << 4;
      f32x4 va = *(const f32x4*)(cb + ((c << 4) ^ swz));
      f32x4 vb = *(const f32x4*)(cb + (((c + 1) << 4) ^ swz));
      float w0 = wc2[di * 3 + 0], w1 = wc2[di * 3 + 1], w2 = wc2[di * 3 + 2];
      res[0] += w0 * va[0] + w1 * va[1] + w2 * va[2];
      res[1] += w0 * va[1] + w1 * va[2] + w2 * va[3];
      res[2] += w0 * va[2] + w1 * va[3] + w2 * vb[0];
      res[3] += w0 * va[3] + w1 * vb[0] + w2 * vb[1];
    }
    u16 pk[4];
#pragma unroll
    for (int e = 0; e < 4; ++e) {
      float val = fmaxf(res[e], 0.f);
      lsum += val;
      pk[e] = f2bf(val);
    }
    *(uint2*)(ab + (size_t)(r0 + ai) * 1024 + s0 + col0) = *(const uint2*)pk;
  }
#pragma unroll
  for (int off = 32; off; off >>= 1) lsum += __shfl_xor(lsum, off);
  if (l == 0) wred[w] = lsum;
  __syncthreads();
  if (tid == 0) partial[bid] = wred[0] + wred[1] + wred[2] + wred[3];
}

// ---------------- K3: SE gate (cw) ----------------
__global__ __launch_bounds__(256) void mha_cw(const float* __restrict__ partial,
                                              const float* __restrict__ w1,
                                              const float* __restrict__ b1,
                                              const float* __restrict__ w2,
                                              const float* __restrict__ b2,
                                              float* __restrict__ cw) {
  __shared__ float sums[24];
  int t = threadIdx.x;
  if (t < 192) {
    int bh = t >> 3, i = t & 7;
    const float* p = partial + bh * 256 + i * 32;
    float s = 0.f;
#pragma unroll
    for (int k = 0; k < 32; ++k) s += p[k];
    s += __shfl_xor(s, 1);
    s += __shfl_xor(s, 2);
    s += __shfl_xor(s, 4);
    if (i == 0) sums[bh] = s;
  }
  __syncthreads();
  if (t < 24) {
    int b = t / 3, h = t - 3 * b;
    float pm0 = sums[b * 3 + 0] * (1.f / 1048576.f);
    float pm1 = sums[b * 3 + 1] * (1.f / 1048576.f);
    float pm2 = sums[b * 3 + 2] * (1.f / 1048576.f);
    float hid = pm0 * w1[0] + pm1 * w1[1] + pm2 * w1[2] + b1[0];
    hid = fmaxf(hid, 0.f);
    float z = hid * w2[h] + b2[h];
    cw[t] = 1.f / (1.f + __expf(-z));
  }
}

// ---------------- K5: softmax(cw*a) + PV ----------------
// grid 768 = bh(24)*rowblock(32); 512 threads (8 waves). Dynamic LDS 65664 B:
//   [0,65536)      P 32x1024 bf16, 16B chunks XOR-swizzled by ((row&7)<<4)
//   [65536,65664)  reds[32] f32 row sums
// No max subtraction: a>=0 and bounded (~1.5), cw in (0,1) -> exp safe in f32.
__global__ __launch_bounds__(512) void mha_smpv(const u16* __restrict__ a,
                                                const u16* __restrict__ vt,
                                                const float* __restrict__ cw,
                                                float* __restrict__ o) {
  extern __shared__ char smem[];
  float* reds = (float*)(smem + 65536);
  int bid = blockIdx.x;
  int rb = bid & 31, bh = bid >> 5;
  int b = bh / 3, h = bh - 3 * b;
  int n0 = rb * 32;
  int tid = threadIdx.x, w = tid >> 6, l = tid & 63;
  float cwv = cw[bh];
  const u16* ab = a + (size_t)bh * 1048576 + (size_t)n0 * 1024;
  // exp pass: row owned by one 16-lane group
  int row = w * 4 + (l >> 4);
  int seg = l & 15;
  const u16* arp = ab + (size_t)row * 1024;
  float lsum = 0.f;
#pragma unroll
  for (int pass = 0; pass < 8; ++pass) {
    int col = pass * 128 + seg * 8;
    uint4 vv = *(const uint4*)(arp + col);
    const u16* pv = (const u16*)&vv;
    u16 pk[8];
#pragma unroll
    for (int e = 0; e < 8; ++e) {
      float ex = __expf(bf2f(pv[e]) * cwv);
      u16 qq = f2bf(ex);
      lsum += bf2f(qq);
      pk[e] = qq;
    }
    int chunk = pass * 16 + seg;
    *(uint4*)(smem + row * 2048 + ((chunk << 4) ^ ((row & 7) << 4))) = *(const uint4*)pk;
  }
  lsum += __shfl_xor(lsum, 1);
  lsum += __shfl_xor(lsum, 2);
  lsum += __shfl_xor(lsum, 4);
  lsum += __shfl_xor(lsum, 8);
  if (seg == 0) reds[row] = lsum;
  __syncthreads();
  // PV: wave -> (colt = w&3, rt = w>>2) 16x16 output tile, K=1024
  int colt = w & 3, rt = w >> 2;
  int lr = l & 15, lg = l >> 4;
  const u16* vb = vt + ((size_t)bh * 64 + colt * 16 + lr) * 1024;
  f32x4 acc = {0.f, 0.f, 0.f, 0.f};
  for (int kt = 0; kt < 32; ++kt) {
    int arow = rt * 16 + lr;
    int ch = kt * 4 + lg;
    uint4 afr = *(const uint4*)(smem + arow * 2048 + ((ch << 4) ^ ((arow & 7) << 4)));
    uint4 bfr = *(const uint4*)(vb + kt * 32 + lg * 8);
    acc = __builtin_amdgcn_mfma_f32_16x16x32_bf16(asfrag(afr), asfrag(bfr), acc, 0, 0, 0);
  }
  float* ob = o + (size_t)(b * 1024 + n0) * 192 + h * 64 + colt * 16 + lr;
#pragma unroll
  for (int r = 0; r < 4; ++r) {
    int rr = rt * 16 + 4 * lg + r;
    ob[(size_t)rr * 192] = acc[r] / reds[rr];
  }
}

// ---------------- K6: output projection (fp32 vector) ----------------
// grid (128, 3); 256 threads; each thread a 4x4 output tile. LDS stride 193.
__global__ __launch_bounds__(256) void mha_proj(const float* __restrict__ o,
                                                const float* __restrict__ W,
                                                const float* __restrict__ bo,
                                                float* __restrict__ out) {
  __shared__ float ot[64 * 193];
  int nb = blockIdx.x, cb = blockIdx.y;
  int t = threadIdx.x;
#pragma unroll
  for (int it = 0; it < 48; ++it) {
    int idx = t + it * 256;
    int row = idx / 192, c = idx - row * 192;
    ot[row * 193 + c] = o[(size_t)(nb * 64 + row) * 192 + c];
  }
  __syncthreads();
  int r0 = (t >> 4) * 4;
  int c0 = cb * 64 + (t & 15) * 4;
  float acc[4][4];
#pragma unroll
  for (int i = 0; i < 4; ++i)
#pragma unroll
    for (int j = 0; j < 4; ++j) acc[i][j] = 0.f;
  for (int kx = 0; kx < 192; ++kx) {
    f32x4 wv = *(const f32x4*)(W + (size_t)kx * 192 + c0);
    float ov[4];
#pragma unroll
    for (int i = 0; i < 4; ++i) ov[i] = ot[(r0 + i) * 193 + kx];
#pragma unroll
    for (int i = 0; i < 4; ++i)
#pragma unroll
      for (int j = 0; j < 4; ++j) acc[i][j] += ov[i] * wv[j];
  }
  float4 bv = *(const float4*)(bo + c0);
#pragma unroll
  for (int i = 0; i < 4; ++i) {
    float4 res = {acc[i][0] + bv.x, acc[i][1] + bv.y, acc[i][2] + bv.z, acc[i][3] + bv.w};
    *(float4*)(out + (size_t)(nb * 64 + r0 + i) * 192 + c0) = res;
  }
}

extern "C" void kernel_launch(void* const* d_in, const int* in_sizes, int n_in,
                              void* d_out, int out_size, void* d_ws, size_t ws_size,
                              hipStream_t stream) {
  (void)in_sizes; (void)n_in; (void)out_size; (void)ws_size;
  const float* x    = (const float*)d_in[0];
  const float* wqkv = (const float*)d_in[1];
  const float* c1w  = (const float*)d_in[2];
  const float* c1b  = (const float*)d_in[3];
  const float* g1   = (const float*)d_in[4];
  const float* b1   = (const float*)d_in[5];
  const float* c2w  = (const float*)d_in[6];
  const float* c2b  = (const float*)d_in[7];
  const float* g2   = (const float*)d_in[8];
  const float* b2   = (const float*)d_in[9];
  const float* caw1 = (const float*)d_in[10];
  const float* cab1 = (const float*)d_in[11];
  const float* caw2 = (const float*)d_in[12];
  const float* cab2 = (const float*)d_in[13];
  const float* wout = (const float*)d_in[14];
  const float* bout = (const float*)d_in[15];
  float* out = (float*)d_out;
  char* ws = (char*)d_ws;

  // partial/cw overlap the xb region (xb is dead after K1; K2 runs after K1).
  float* partial = (float*)(ws + 0);        // 6144 f32 = 24,576 B
  float* cwbuf   = (float*)(ws + 24576);    // 24 f32
  u16* xb = (u16*)(ws + 0);
  u16* wt = (u16*)(ws + 3145728);
  u16* q  = (u16*)(ws + 3366912);
  u16* k  = (u16*)(ws + 6512640);
  u16* vt = (u16*)(ws + 9658368);
  u16* a  = (u16*)(ws + 12804096);
  float* o = (float*)(ws + 63135744);

  mha_cvt_x<<<1536, 256, 0, stream>>>(x, xb);
  mha_wt<<<432, 256, 0, stream>>>(wqkv, wt);
  mha_qkv<<<dim3(128, 3), 256, 0, stream>>>(xb, wt, q, k, vt);
  mha_qkconv<<<6144, 256, 0, stream>>>(q, k, c1w, c1b, g1, b1, c2w, c2b, g2, b2, a, partial);
  mha_cw<<<1, 256, 0, stream>>>(partial, caw1, cab1, caw2, cab2, cwbuf);
  hipFuncSetAttribute(reinterpret_cast<const void*>(mha_smpv),
                      hipFuncAttributeMaxDynamicSharedMemorySize, 65664);
  mha_smpv<<<768, 512, 65664, stream>>>(a, vt, cwbuf, o);
  mha_proj<<<dim3(128, 3), 256, 0, stream>>>(o, wout, bout, out);
}

// Round 3
// 133.277 us; speedup vs baseline: 1.1224x; 1.0921x over previous
//
#include <hip/hip_runtime.h>

// MultiHeadAttention fused pipeline for MI355X (gfx950).
// B=8, N=1024, DIM=192, HEADS=3, DH=64.
//
// Workspace layout (bytes):
//   partial @ 0         : 24,576     [bh][256] f32 SE-pool partials
//   wt      @ 3,145,728 : 221,184    W_qkv^T bf16 [576][192]
//   q       @ 3,366,912 : 3,145,728  [bh][n][d] bf16
//   k       @ 6,512,640 : 3,145,728  [bh][n][d] bf16
//   vt      @ 9,658,368 : 3,145,728  [bh][d][n] bf16
//   a       @ 12,804,096: 50,331,648 [bh][i][j] bf16
//   o       @ 63,135,744: 6,291,456  [n][h*64+d] f32

typedef unsigned short u16;
typedef unsigned int u32;
using f32x4 = __attribute__((ext_vector_type(4))) float;
using short8 = __attribute__((ext_vector_type(8))) short;

__device__ inline u16 f2bf(float f) {
  u32 u = __builtin_bit_cast(u32, f);
  u32 r = (u + 0x7FFFu + ((u >> 16) & 1u)) >> 16;
  return (u16)r;
}
__device__ inline float bf2f(u16 v) {
  u32 u = ((u32)v) << 16;
  return __builtin_bit_cast(float, u);
}
__device__ inline short8 asfrag(uint4 v) { return __builtin_bit_cast(short8, v); }

// ---------------- K0: transpose W_qkv -> wt bf16 [576][192] ----------------
__global__ __launch_bounds__(256) void mha_wt(const float* __restrict__ wq,
                                              u16* __restrict__ wt) {
  int i = blockIdx.x * 256 + threadIdx.x;
  int c = i / 192, kk = i - c * 192;
  wt[i] = f2bf(wq[(size_t)kk * 576 + c]);
}

// ---------------- K1: qkv projection (reads x f32 directly) ----------------
// grid (128,3): x-block = 64 rows; y: 0->q, 1->k, 2->v (stored transposed).
__global__ __launch_bounds__(256) void mha_qkv(const float* __restrict__ x,
                                               const u16* __restrict__ wt,
                                               u16* __restrict__ q,
                                               u16* __restrict__ kmat,
                                               u16* __restrict__ vt) {
  __shared__ u16 tile[64][72];
  int mb = blockIdx.x, gy = blockIdx.y;
  int tid = threadIdx.x, w = tid >> 6, l = tid & 63;
  int lr = l & 15, lg = l >> 4;
  int m0 = mb * 64 + w * 16;
  const float* xrow = x + (size_t)(m0 + lr) * 192;
  uint4 af[6];
#pragma unroll
  for (int s = 0; s < 6; ++s) {
    float4 a0 = *(const float4*)(xrow + s * 32 + lg * 8);
    float4 a1 = *(const float4*)(xrow + s * 32 + lg * 8 + 4);
    u16 pk[8] = {f2bf(a0.x), f2bf(a0.y), f2bf(a0.z), f2bf(a0.w),
                 f2bf(a1.x), f2bf(a1.y), f2bf(a1.z), f2bf(a1.w)};
    af[s] = *(const uint4*)pk;
  }
  int b = mb >> 4, n0 = (mb & 15) << 6;
  for (int i = 0; i < 3; ++i) {
    int nt = gy * 3 + i;
#pragma unroll
    for (int ct = 0; ct < 4; ++ct) {
      int c = nt * 64 + ct * 16 + lr;
      const u16* wrow = wt + (size_t)c * 192;
      f32x4 acc = {0.f, 0.f, 0.f, 0.f};
#pragma unroll
      for (int s = 0; s < 6; ++s) {
        uint4 bf = *(const uint4*)(wrow + s * 32 + lg * 8);
        acc = __builtin_amdgcn_mfma_f32_16x16x32_bf16(asfrag(af[s]), asfrag(bf), acc, 0, 0, 0);
      }
#pragma unroll
      for (int r = 0; r < 4; ++r) tile[w * 16 + 4 * lg + r][ct * 16 + lr] = f2bf(acc[r]);
    }
    __syncthreads();
    size_t bh = (size_t)(b * 3 + i);
    if (gy < 2) {
      u16* dst = (gy == 0 ? q : kmat) + bh * 65536;
#pragma unroll
      for (int it = 0; it < 2; ++it) {
        int id = tid + it * 256;
        int rr = id >> 3, ch = id & 7;
        uint4 vv = *(const uint4*)&tile[rr][ch * 8];
        *(uint4*)(dst + (size_t)(n0 + rr) * 64 + ch * 8) = vv;
      }
    } else {
      u16* dst = vt + bh * 65536;
#pragma unroll
      for (int it = 0; it < 2; ++it) {
        int id = tid + it * 256;
        int d = id >> 3, ch = id & 7;
        u16 pk[8];
#pragma unroll
        for (int e = 0; e < 8; ++e) pk[e] = tile[ch * 8 + e][d];
        *(uint4*)(dst + (size_t)d * 1024 + n0 + ch * 8) = *(const uint4*)pk;
      }
    }
    __syncthreads();
  }
}

// ---------------- K2: fused QK^T + conv1+bn+relu + conv2+bn+relu + pool ----------------
// grid 6144 = bh(24)*rowblock(32)*colstrip(8); 256 threads. 32x128 output tile.
// S bf16 [37][136] (rows r0-2..r0+33, cols s0-2..s0+129; row 36 = pad).
// C1 f32 [34][136] (rows r0-1..r0+32, cols s0-1..s0+128 at local 0..129).
// Phase 1 computes T = K*Q^T so each lane holds 4 consecutive S-cols -> b64 writes.
__global__ __launch_bounds__(256) void mha_qkconv(
    const u16* __restrict__ q, const u16* __restrict__ kmat,
    const float* __restrict__ c1w, const float* __restrict__ c1b,
    const float* __restrict__ g1, const float* __restrict__ bb1,
    const float* __restrict__ c2w, const float* __restrict__ c2b,
    const float* __restrict__ g2, const float* __restrict__ bb2,
    u16* __restrict__ a, float* __restrict__ partial) {
  __shared__ u16 S[37 * 136];
  __shared__ float C1[34 * 136];
  __shared__ float wred[4];
  int bid = blockIdx.x;
  int st = bid & 7, rb = (bid >> 3) & 31, bh = bid >> 8;
  int h = bh - (bh / 3) * 3;
  int r0 = rb * 32, s0 = st * 128;
  int tid = threadIdx.x, w = tid >> 6, l = tid & 63;
  int lr = l & 15, lg = l >> 4;
  const u16* qb = q + (size_t)bh * 65536;
  const u16* kb = kmat + (size_t)bh * 65536;
  // ---- phase 1: T = K*Q^T (so S[i][j] with j contiguous per lane) ----
  uint4 bq[3][2];
#pragma unroll
  for (int it = 0; it < 3; ++it) {
    int gi = r0 - 2 + 16 * it + lr;
    bool ok = (gi >= 0) && (gi < 1024);
#pragma unroll
    for (int kk = 0; kk < 2; ++kk)
      bq[it][kk] = ok ? *(const uint4*)(qb + (size_t)gi * 64 + kk * 32 + lg * 8)
                      : make_uint4(0, 0, 0, 0);
  }
#pragma unroll
  for (int t = 0; t < 3; ++t) {
    int jt = w + 4 * t;
    if (jt >= 9) break;
    int gj = s0 - 2 + 16 * jt + lr;
    bool ok = (gj >= 0) && (gj < 1024);
    uint4 ak0 = ok ? *(const uint4*)(kb + (size_t)gj * 64 + lg * 8) : make_uint4(0, 0, 0, 0);
    uint4 ak1 = ok ? *(const uint4*)(kb + (size_t)gj * 64 + 32 + lg * 8) : make_uint4(0, 0, 0, 0);
    int sj = 16 * jt + 4 * lg;
    int si = 16 * 0 + lr;  // varies with it below
#pragma unroll
    for (int it = 0; it < 3; ++it) {
      f32x4 acc = {0.f, 0.f, 0.f, 0.f};
      acc = __builtin_amdgcn_mfma_f32_16x16x32_bf16(asfrag(ak0), asfrag(bq[it][0]), acc, 0, 0, 0);
      acc = __builtin_amdgcn_mfma_f32_16x16x32_bf16(asfrag(ak1), asfrag(bq[it][1]), acc, 0, 0, 0);
      si = 16 * it + lr;
      if (si < 36 && sj < 132) {
        u16 pk[4] = {f2bf(acc[0] * 0.125f), f2bf(acc[1] * 0.125f),
                     f2bf(acc[2] * 0.125f), f2bf(acc[3] * 0.125f)};
        *(uint2*)&S[si * 136 + sj] = *(const uint2*)pk;
      }
    }
  }
  __syncthreads();
  // ---- phase 2: conv1+bn+relu -> C1 (f32), vertical rolling window ----
  float sc1 = g1[h] / sqrtf(1.00001f);
  float wc1[9];
#pragma unroll
  for (int i = 0; i < 9; ++i) wc1[i] = c1w[h * 9 + i] * sc1;
  float bias1 = c1b[h] * sc1 + bb1[h];
  if (tid < 231) {
    int rs = tid / 33;
    int cg = tid - rs * 33;
    int base = (rs < 6) ? rs * 5 : 30;
    int c0 = cg * 4;
    float cm[4];
#pragma unroll
    for (int e = 0; e < 4; ++e) {
      int gc = s0 - 1 + c0 + e;
      cm[e] = (gc >= 0 && gc < 1024) ? 1.f : 0.f;
    }
    float win[3][6];
    // load S rows base, base+1
#pragma unroll
    for (int rr = 0; rr < 2; ++rr) {
      uint2 d0 = *(const uint2*)&S[(base + rr) * 136 + c0];
      uint2 d1 = *(const uint2*)&S[(base + rr) * 136 + c0 + 4];
      const u16* p0 = (const u16*)&d0;
      const u16* p1 = (const u16*)&d1;
#pragma unroll
      for (int e = 0; e < 4; ++e) win[rr][e] = bf2f(p0[e]);
      win[rr][4] = bf2f(p1[0]);
      win[rr][5] = bf2f(p1[1]);
    }
#pragma unroll
    for (int i = 0; i < 5; ++i) {
      int srow = base + i + 2;
      uint2 d0 = *(const uint2*)&S[srow * 136 + c0];
      uint2 d1 = *(const uint2*)&S[srow * 136 + c0 + 4];
      const u16* p0 = (const u16*)&d0;
      const u16* p1 = (const u16*)&d1;
      int wi = (i + 2) % 3;
#pragma unroll
      for (int e = 0; e < 4; ++e) win[wi][e] = bf2f(p0[e]);
      win[wi][4] = bf2f(p1[0]);
      win[wi][5] = bf2f(p1[1]);
      int ci = base + i;
      int gr = r0 - 1 + ci;
      float rm = (gr >= 0 && gr < 1024) ? 1.f : 0.f;
      const float* v0 = win[i % 3];
      const float* v1 = win[(i + 1) % 3];
      const float* v2 = win[(i + 2) % 3];
      f32x4 res = {bias1, bias1, bias1, bias1};
#pragma unroll
      for (int e = 0; e < 4; ++e) {
        res[e] += wc1[0] * v0[e] + wc1[1] * v0[e + 1] + wc1[2] * v0[e + 2];
        res[e] += wc1[3] * v1[e] + wc1[4] * v1[e + 1] + wc1[5] * v1[e + 2];
        res[e] += wc1[6] * v2[e] + wc1[7] * v2[e + 1] + wc1[8] * v2[e + 2];
        res[e] = fmaxf(res[e], 0.f) * rm * cm[e];
      }
      if (ci < 34) *(f32x4*)&C1[ci * 136 + c0] = res;
    }
  }
  __syncthreads();
  // ---- phase 3: conv2+bn+relu -> a (bf16 global) + pool, rolling window ----
  float sc2 = g2[h] / sqrtf(1.00001f);
  float wc2[9];
#pragma unroll
  for (int i = 0; i < 9; ++i) wc2[i] = c2w[h * 9 + i] * sc2;
  float bias2 = c2b[h] * sc2 + bb2[h];
  int rs3 = tid >> 5, cg3 = tid & 31;
  int j0 = cg3 * 4;
  int rbase = rs3 * 4;
  float lsum = 0.f;
  u16* ab = a + (size_t)bh * 1048576 + (size_t)r0 * 1024 + s0 + j0;
  float win2[3][6];
#pragma unroll
  for (int rr = 0; rr < 2; ++rr) {
    f32x4 d0 = *(const f32x4*)&C1[(rbase + rr) * 136 + j0];
    f32x4 d1 = *(const f32x4*)&C1[(rbase + rr) * 136 + j0 + 4];
#pragma unroll
    for (int e = 0; e < 4; ++e) win2[rr][e] = d0[e];
    win2[rr][4] = d1[0];
    win2[rr][5] = d1[1];
  }
#pragma unroll
  for (int i = 0; i < 4; ++i) {
    int crow = rbase + i + 2;
    f32x4 d0 = *(const f32x4*)&C1[crow * 136 + j0];
    f32x4 d1 = *(const f32x4*)&C1[crow * 136 + j0 + 4];
    int wi = (i + 2) % 3;
#pragma unroll
    for (int e = 0; e < 4; ++e) win2[wi][e] = d0[e];
    win2[wi][4] = d1[0];
    win2[wi][5] = d1[1];
    const float* v0 = win2[i % 3];
    const float* v1 = win2[(i + 1) % 3];
    const float* v2 = win2[(i + 2) % 3];
    f32x4 res = {bias2, bias2, bias2, bias2};
    u16 pk[4];
#pragma unroll
    for (int e = 0; e < 4; ++e) {
      res[e] += wc2[0] * v0[e] + wc2[1] * v0[e + 1] + wc2[2] * v0[e + 2];
      res[e] += wc2[3] * v1[e] + wc2[4] * v1[e + 1] + wc2[5] * v1[e + 2];
      res[e] += wc2[6] * v2[e] + wc2[7] * v2[e + 1] + wc2[8] * v2[e + 2];
      float val = fmaxf(res[e], 0.f);
      lsum += val;
      pk[e] = f2bf(val);
    }
    *(uint2*)(ab + (size_t)i * 1024) = *(const uint2*)pk;
  }
#pragma unroll
  for (int off = 32; off; off >>= 1) lsum += __shfl_xor(lsum, off);
  if (l == 0) wred[w] = lsum;
  __syncthreads();
  if (tid == 0) partial[bid] = wred[0] + wred[1] + wred[2] + wred[3];
}

// ---------------- K3: SE gate + softmax(cw*a) + PV ----------------
// grid 768 = bh(24)*rowblock(32); 512 threads (8 waves). Dynamic LDS 65696 B:
//   [0,65536)      P 32x1024 bf16, 16B chunks XOR-swizzled by ((row&7)<<4)
//   [65536,65664)  reds[32] f32 row sums
//   [65664,65680)  pm[3] f32 head pool sums
__global__ __launch_bounds__(512) void mha_smpv(
    const u16* __restrict__ a, const u16* __restrict__ vt,
    const float* __restrict__ partial,
    const float* __restrict__ caw1, const float* __restrict__ cab1,
    const float* __restrict__ caw2, const float* __restrict__ cab2,
    float* __restrict__ o) {
  extern __shared__ char smem[];
  float* reds = (float*)(smem + 65536);
  float* pm = (float*)(smem + 65664);
  int bid = blockIdx.x;
  int rb = bid & 31, bh = bid >> 5;
  int b = bh / 3, h = bh - 3 * b;
  int n0 = rb * 32;
  int tid = threadIdx.x, w = tid >> 6, l = tid & 63;
  // SE pool: waves 0-2 reduce one head each
  if (w < 3) {
    const float* p = partial + (size_t)(b * 3 + w) * 256;
    float s = p[l] + p[l + 64] + p[l + 128] + p[l + 192];
#pragma unroll
    for (int off = 32; off; off >>= 1) s += __shfl_xor(s, off);
    if (l == 0) pm[w] = s;
  }
  __syncthreads();
  float pm0 = pm[0] * (1.f / 1048576.f);
  float pm1 = pm[1] * (1.f / 1048576.f);
  float pm2 = pm[2] * (1.f / 1048576.f);
  float hid = fmaxf(pm0 * caw1[0] + pm1 * caw1[1] + pm2 * caw1[2] + cab1[0], 0.f);
  float cwv = 1.f / (1.f + __expf(-(hid * caw2[h] + cab2[h])));
  const u16* ab = a + (size_t)bh * 1048576 + (size_t)n0 * 1024;
  // exp pass: row owned by one 16-lane group
  int row = w * 4 + (l >> 4);
  int seg = l & 15;
  const u16* arp = ab + (size_t)row * 1024;
  float lsum = 0.f;
#pragma unroll
  for (int pass = 0; pass < 8; ++pass) {
    int col = pass * 128 + seg * 8;
    uint4 vv = *(const uint4*)(arp + col);
    const u16* pv = (const u16*)&vv;
    u16 pk[8];
#pragma unroll
    for (int e = 0; e < 8; ++e) {
      float ex = __expf(bf2f(pv[e]) * cwv);
      u16 qq = f2bf(ex);
      lsum += bf2f(qq);
      pk[e] = qq;
    }
    int chunk = pass * 16 + seg;
    *(uint4*)(smem + row * 2048 + ((chunk << 4) ^ ((row & 7) << 4))) = *(const uint4*)pk;
  }
  lsum += __shfl_xor(lsum, 1);
  lsum += __shfl_xor(lsum, 2);
  lsum += __shfl_xor(lsum, 4);
  lsum += __shfl_xor(lsum, 8);
  if (seg == 0) reds[row] = lsum;
  __syncthreads();
  // PV: wave -> (colt = w&3, rt = w>>2) 16x16 output tile, K=1024
  int colt = w & 3, rt = w >> 2;
  int lr = l & 15, lg = l >> 4;
  const u16* vb = vt + ((size_t)bh * 64 + colt * 16 + lr) * 1024;
  f32x4 acc = {0.f, 0.f, 0.f, 0.f};
  for (int kt = 0; kt < 32; ++kt) {
    int arow = rt * 16 + lr;
    int ch = kt * 4 + lg;
    uint4 afr = *(const uint4*)(smem + arow * 2048 + ((ch << 4) ^ ((arow & 7) << 4)));
    uint4 bfr = *(const uint4*)(vb + kt * 32 + lg * 8);
    acc = __builtin_amdgcn_mfma_f32_16x16x32_bf16(asfrag(afr), asfrag(bfr), acc, 0, 0, 0);
  }
  float* ob = o + (size_t)(b * 1024 + n0) * 192 + h * 64 + colt * 16 + lr;
#pragma unroll
  for (int r = 0; r < 4; ++r) {
    int rr = rt * 16 + 4 * lg + r;
    ob[(size_t)rr * 192] = acc[r] / reds[rr];
  }
}

// ---------------- K4: output projection (fp32, LDS-free register tiles) ----------------
// grid (128, 3); 256 threads; each thread a 4x4 output tile; o reads L1/L2-broadcast.
__global__ __launch_bounds__(256) void mha_proj(const float* __restrict__ o,
                                                const float* __restrict__ W,
                                                const float* __restrict__ bo,
                                                float* __restrict__ out) {
  int nb = blockIdx.x, cb = blockIdx.y;
  int t = threadIdx.x;
  int r0 = nb * 64 + (t >> 4) * 4;
  int c0 = cb * 64 + (t & 15) * 4;
  const float* orow = o + (size_t)r0 * 192;
  float acc[4][4];
#pragma unroll
  for (int i = 0; i < 4; ++i)
#pragma unroll
    for (int j = 0; j < 4; ++j) acc[i][j] = 0.f;
  for (int kx = 0; kx < 192; kx += 4) {
    f32x4 ov[4], wv[4];
#pragma unroll
    for (int i = 0; i < 4; ++i) ov[i] = *(const f32x4*)(orow + (size_t)i * 192 + kx);
#pragma unroll
    for (int kk = 0; kk < 4; ++kk) wv[kk] = *(const f32x4*)(W + (size_t)(kx + kk) * 192 + c0);
#pragma unroll
    for (int i = 0; i < 4; ++i)
#pragma unroll
      for (int kk = 0; kk < 4; ++kk)
#pragma unroll
        for (int j = 0; j < 4; ++j) acc[i][j] += ov[i][kk] * wv[kk][j];
  }
  f32x4 bv = *(const f32x4*)(bo + c0);
#pragma unroll
  for (int i = 0; i < 4; ++i) {
    f32x4 res = {acc[i][0] + bv[0], acc[i][1] + bv[1], acc[i][2] + bv[2], acc[i][3] + bv[3]};
    *(f32x4*)(out + (size_t)(r0 + i) * 192 + c0) = res;
  }
}

extern "C" void kernel_launch(void* const* d_in, const int* in_sizes, int n_in,
                              void* d_out, int out_size, void* d_ws, size_t ws_size,
                              hipStream_t stream) {
  (void)in_sizes; (void)n_in; (void)out_size; (void)ws_size;
  const float* x    = (const float*)d_in[0];
  const float* wqkv = (const float*)d_in[1];
  const float* c1w  = (const float*)d_in[2];
  const float* c1b  = (const float*)d_in[3];
  const float* g1   = (const float*)d_in[4];
  const float* b1   = (const float*)d_in[5];
  const float* c2w  = (const float*)d_in[6];
  const float* c2b  = (const float*)d_in[7];
  const float* g2   = (const float*)d_in[8];
  const float* b2   = (const float*)d_in[9];
  const float* caw1 = (const float*)d_in[10];
  const float* cab1 = (const float*)d_in[11];
  const float* caw2 = (const float*)d_in[12];
  const float* cab2 = (const float*)d_in[13];
  const float* wout = (const float*)d_in[14];
  const float* bout = (const float*)d_in[15];
  float* out = (float*)d_out;
  char* ws = (char*)d_ws;

  float* partial = (float*)(ws + 0);
  u16* wt = (u16*)(ws + 3145728);
  u16* q  = (u16*)(ws + 3366912);
  u16* k  = (u16*)(ws + 6512640);
  u16* vt = (u16*)(ws + 9658368);
  u16* a  = (u16*)(ws + 12804096);
  float* o = (float*)(ws + 63135744);

  mha_wt<<<432, 256, 0, stream>>>(wqkv, wt);
  mha_qkv<<<dim3(128, 3), 256, 0, stream>>>(x, wt, q, k, vt);
  mha_qkconv<<<6144, 256, 0, stream>>>(q, k, c1w, c1b, g1, b1, c2w, c2b, g2, b2, a, partial);
  hipFuncSetAttribute(reinterpret_cast<const void*>(mha_smpv),
                      hipFuncAttributeMaxDynamicSharedMemorySize, 65696);
  mha_smpv<<<768, 512, 65696, stream>>>(a, vt, partial, caw1, cab1, caw2, cab2, o);
  mha_proj<<<dim3(128, 3), 256, 0, stream>>>(o, wout, bout, out);
}